// Round 5
// baseline (474.217 us; speedup 1.0000x reference)
//
#include <hip/hip_runtime.h>
#include <math.h>

// CRF mean-field, fully factorized — NO O(N^2) pass.
// Single persistent kernel + RMW-FREE, FENCE-FREE grid barrier.
// Barrier post-mortems: R1/R2 acquire-polling -> per-poll L2 invalidate storm.
// R3/R4 fetch_add(0) polling -> same-line far-atomic RMWs SERIALIZE at the
// coherence point (~30 us/barrier queue). This version: arrive = relaxed
// atomic STORE to a per-block flag; manager block 0 polls 115 distinct lines
// with relaxed atomic LOADS (broadcastable, no serialization, no cache ops);
// go = one relaxed store, polled by relaxed loads. Data ordering: sc1
// write-through stores are acked at the coherence point before __syncthreads
// releases thread 0 to set the flag; consumers read sc1 from the same point.
// Cross-phase MUTABLE data via relaxed agent(sc1) loads/stores; read-only data
// (M rows, scale1/2, inputs) normally L2-cached, never invalidated.
// Staging loads explicitly prefetched 16-deep into registers (MLP guarantee).
// Bilateral kernel rank-28 Taylor basis (degree 6), separable 3-D Gaussian
// convs, 5 mean-field iterations. N = 32*16*16 = 8192, C = 4.

constexpr int   NT    = 8192;
constexpr float LOG2E = 1.4426950408889634f;
constexpr float SQL2E = 1.2011224087864498f;     // sqrt(log2 e)
constexpr float INVA  = 0.2f * SQL2E;            // spatial prescale

// W rows (NT floats each):
//   0..27  : M[ab]   28..31 : sync flags area   32..35 u1[c]
//   36..39 u2[c]   40 scale1  41 scale2  42..157 conv outputs
constexpr int R_M = 0, R_SY = 28, R_U1 = 32, R_U2 = 36, R_S1 = 40, R_S2 = 41, R_CV = 42;
constexpr int NBLK = 116;                         // 112 bilateral + 4 spatial vols
constexpr int PPB  = (NT + NBLK - 1) / NBLK;      // 71 points/block, pointwise phases

static __device__ __forceinline__ float ex2(float x) {
    return __builtin_amdgcn_exp2f(x);
}

// Coherence-point (agent/sc1) access for cross-phase mutable data. Relaxed ->
// plain global_load/store with sc1 bits, NO buffer_inv / buffer_wbl2, NO RMW.
static __device__ __forceinline__ float ldcp(const float* p) {
    return __hip_atomic_load(p, __ATOMIC_RELAXED, __HIP_MEMORY_SCOPE_AGENT);
}
static __device__ __forceinline__ void stcp(float* p, float v) {
    __hip_atomic_store(p, v, __ATOMIC_RELAXED, __HIP_MEMORY_SCOPE_AGENT);
}
static __device__ __forceinline__ unsigned ldcpu(const unsigned* p) {
    return __hip_atomic_load(p, __ATOMIC_RELAXED, __HIP_MEMORY_SCOPE_AGENT);
}
static __device__ __forceinline__ void stcpu(unsigned* p, unsigned v) {
    __hip_atomic_store(p, v, __ATOMIC_RELAXED, __HIP_MEMORY_SCOPE_AGENT);
}

__constant__ float INVSQF[7] = {1.f, 1.f, 0.70710678f, 0.40824829f,
                                0.20412415f, 0.09128709f, 0.03726780f};
// ab -> (a,b) enumeration: for k=0..6, a=k..0, b=k-a  (must match contract order)
__constant__ int AB_A[28] = {0, 1,0, 2,1,0, 3,2,1,0, 4,3,2,1,0,
                             5,4,3,2,1,0, 6,5,4,3,2,1,0};
__constant__ int AB_B[28] = {0, 0,1, 0,1,2, 0,1,2,3, 0,1,2,3,4,
                             0,1,2,3,4,5, 0,1,2,3,4,5,6};

// ------------------------- RMW-free fenceless grid barrier ------------------
// sync[0]            : go word (relaxed store by manager, relaxed-load polled)
// sync[256 + b*16]   : arrive flag of block b (64 B padded, distinct lines)
static __device__ __forceinline__ void gsync(unsigned* sync, unsigned gen) {
    __syncthreads();                 // vmcnt(0): all sc1 data stores acked
    if (blockIdx.x == 0) {
        if (threadIdx.x >= 1 && threadIdx.x < NBLK) {
            const unsigned* f = sync + 256 + threadIdx.x * 16;
            while (ldcpu(f) < gen) __builtin_amdgcn_s_sleep(2);
        }
        __syncthreads();             // all 115 flags observed
        if (threadIdx.x == 0) stcpu(sync, gen);
    } else {
        if (threadIdx.x == 0) {
            stcpu(sync + 256 + blockIdx.x * 16, gen);
            while (ldcpu(sync) < gen) __builtin_amdgcn_s_sleep(2);
        }
        __syncthreads();
    }
}

// ---------------- separable 3-D Gaussian conv, 512-thread version -----------
// SP staged as SP[(n>>4)*17 + (n&15)]; caller stages, we sync first.
// Output written via stcp (sc1) — consumed cross-XCD next phase.
static __device__ __forceinline__ void conv3d_store512(float* SP,
                                                       float* __restrict__ outp,
                                                       int tid) {
    float g32[32];
#pragma unroll
    for (int d = 0; d < 32; d++) { float t = d * INVA; g32[d] = ex2(-0.5f*t*t); }
    __syncthreads();
    // z-pass: 512 rows (x,y), one per thread, stride 17
    {
        int r = tid;
        float v[16], acc[16];
#pragma unroll
        for (int z = 0; z < 16; z++) { v[z] = SP[r*17 + z]; acc[z] = 0.f; }
#pragma unroll
        for (int zp = 0; zp < 16; zp++)
#pragma unroll
            for (int z = 0; z < 16; z++) {
                int d = (z > zp) ? (z - zp) : (zp - z);
                acc[z] = fmaf(g32[d], v[zp], acc[z]);
            }
#pragma unroll
        for (int z = 0; z < 16; z++) SP[r*17 + z] = acc[z];
    }
    __syncthreads();
    // y-pass: 512 rows (x,z), one per thread, stride 17 between y's
    {
        int x = tid >> 4, z = tid & 15;
        int base = x * 272 + z;
        float v[16], acc[16];
#pragma unroll
        for (int y = 0; y < 16; y++) { v[y] = SP[base + y*17]; acc[y] = 0.f; }
#pragma unroll
        for (int yp = 0; yp < 16; yp++)
#pragma unroll
            for (int y = 0; y < 16; y++) {
                int d = (y > yp) ? (y - yp) : (yp - y);
                acc[y] = fmaf(g32[d], v[yp], acc[y]);
            }
#pragma unroll
        for (int y = 0; y < 16; y++) SP[base + y*17] = acc[y];
    }
    __syncthreads();
    // x-pass: 256 columns (y,z), 2 threads/column; h wave-uniform (tid>>8)
    // so all g32 indices stay compile-time constants (no scratch spill).
    {
        int c = tid & 255, h = tid >> 8;
        int base = (c >> 4) * 17 + (c & 15);     // 17*y + z
        float v[32];
#pragma unroll
        for (int xp = 0; xp < 32; xp++) v[xp] = SP[base + xp*272];
        float acc[16];
#pragma unroll
        for (int x0 = 0; x0 < 16; x0++) acc[x0] = 0.f;
        if (h == 0) {
#pragma unroll
            for (int xp = 0; xp < 32; xp++)
#pragma unroll
                for (int x0 = 0; x0 < 16; x0++) {
                    int d = (x0 > xp) ? (x0 - xp) : (xp - x0);
                    acc[x0] = fmaf(g32[d], v[xp], acc[x0]);
                }
#pragma unroll
            for (int x0 = 0; x0 < 16; x0++) stcp(&outp[x0*256 + c], acc[x0]);
        } else {
#pragma unroll
            for (int xp = 0; xp < 32; xp++)
#pragma unroll
                for (int x0 = 0; x0 < 16; x0++) {
                    int x = x0 + 16;
                    int d = (x > xp) ? (x - xp) : (xp - x);
                    acc[x0] = fmaf(g32[d], v[xp], acc[x0]);
                }
#pragma unroll
            for (int x0 = 0; x0 < 16; x0++) stcp(&outp[(x0+16)*256 + c], acc[x0]);
        }
    }
}

// ---------------- separable 3-D conv, 256-thread version (fallback path) ----
static __device__ __forceinline__ void conv3d_store256(float* SP,
                                                       float* __restrict__ outp,
                                                       int tid) {
    float g32[32];
#pragma unroll
    for (int d = 0; d < 32; d++) { float t = d * INVA; g32[d] = ex2(-0.5f*t*t); }
    __syncthreads();
#pragma unroll
    for (int rr = 0; rr < 2; rr++) {
        int r = tid + rr * 256;
        float v[16], acc[16];
#pragma unroll
        for (int z = 0; z < 16; z++) { v[z] = SP[r*17 + z]; acc[z] = 0.f; }
#pragma unroll
        for (int zp = 0; zp < 16; zp++)
#pragma unroll
            for (int z = 0; z < 16; z++) {
                int d = (z > zp) ? (z - zp) : (zp - z);
                acc[z] = fmaf(g32[d], v[zp], acc[z]);
            }
#pragma unroll
        for (int z = 0; z < 16; z++) SP[r*17 + z] = acc[z];
    }
    __syncthreads();
#pragma unroll
    for (int rr = 0; rr < 2; rr++) {
        int r = tid + rr * 256;
        int x = r >> 4, z = r & 15;
        int base = x * 272 + z;
        float v[16], acc[16];
#pragma unroll
        for (int y = 0; y < 16; y++) { v[y] = SP[base + y*17]; acc[y] = 0.f; }
#pragma unroll
        for (int yp = 0; yp < 16; yp++)
#pragma unroll
            for (int y = 0; y < 16; y++) {
                int d = (y > yp) ? (y - yp) : (yp - y);
                acc[y] = fmaf(g32[d], v[yp], acc[y]);
            }
#pragma unroll
        for (int y = 0; y < 16; y++) SP[base + y*17] = acc[y];
    }
    __syncthreads();
    {
        int base = (tid >> 4) * 17 + (tid & 15);
        float v[32], acc[32];
#pragma unroll
        for (int xp = 0; xp < 32; xp++) { v[xp] = SP[base + xp*272]; acc[xp] = 0.f; }
#pragma unroll
        for (int xp = 0; xp < 32; xp++)
#pragma unroll
            for (int x = 0; x < 32; x++) {
                int d = (x > xp) ? (x - xp) : (xp - x);
                acc[x] = fmaf(g32[d], v[xp], acc[x]);
            }
#pragma unroll
        for (int x = 0; x < 32; x++) outp[x*256 + tid] = acc[x];
    }
}

// ----------------------------- pointwise bodies -----------------------------
// COH=true: persistent-kernel path — mutable rows via sc1 atomics.
template <bool COH>
static __device__ __forceinline__ void init_point(float* __restrict__ W,
                                                  const float* __restrict__ lu,
                                                  int n) {
    float cvv[28];
#pragma unroll
    for (int ab = 0; ab < 28; ab++)
        cvv[ab] = COH ? ldcp(&W[(R_CV+ab)*NT + n]) : W[(R_CV+ab)*NT + n];
    float rs = 0.f;
#pragma unroll
    for (int ab = 0; ab < 28; ab++)
        rs = fmaf(W[(R_M+ab)*NT + n], cvv[ab], rs);
    float s1 = rsqrtf(rs);
    float s2 = W[R_S2*NT + n];
    if (COH) stcp(&W[R_S1*NT + n], s1); else W[R_S1*NT + n] = s1;
    float l0 = lu[n], l1 = lu[NT+n], l2 = lu[2*NT+n], l3 = lu[3*NT+n];
    float mx = fmaxf(fmaxf(l0,l1), fmaxf(l2,l3));
    float q0 = __expf(l0-mx), q1 = __expf(l1-mx), q2 = __expf(l2-mx), q3 = __expf(l3-mx);
    float inv = 1.f / (q0+q1+q2+q3);
    q0*=inv; q1*=inv; q2*=inv; q3*=inv;
    float u1v[4] = {q0*s1, q1*s1, q2*s1, q3*s1};
    float u2v[4] = {q0*s2, q1*s2, q2*s2, q3*s2};
#pragma unroll
    for (int c = 0; c < 4; c++) {
        if (COH) { stcp(&W[(R_U1+c)*NT+n], u1v[c]); stcp(&W[(R_U2+c)*NT+n], u2v[c]); }
        else     { W[(R_U1+c)*NT+n] = u1v[c];       W[(R_U2+c)*NT+n] = u2v[c]; }
    }
}

template <bool COH>
static __device__ __forceinline__ void fuse_point(float* __restrict__ W,
        const float* __restrict__ lu, const float* __restrict__ compat,
        float* __restrict__ out, int n, int last) {
    float s1 = W[R_S1*NT + n], s2 = W[R_S2*NT + n];   // read-only after init
    float q1[4] = {0.f, 0.f, 0.f, 0.f};
#pragma unroll
    for (int ab = 0; ab < 28; ab++) {
        float m = W[(R_M+ab)*NT + n];                 // read-only after phase A
#pragma unroll
        for (int c = 0; c < 4; c++) {
            float cv = COH ? ldcp(&W[(R_CV + ab*4 + c)*NT + n])
                           : W[(R_CV + ab*4 + c)*NT + n];
            q1[c] = fmaf(m, cv, q1[c]);
        }
    }
    float comb[4];
#pragma unroll
    for (int c = 0; c < 4; c++) {
        float cv2 = COH ? ldcp(&W[(R_CV + 112 + c)*NT + n])
                        : W[(R_CV + 112 + c)*NT + n];
        comb[c] = s1 * q1[c] + s2 * cv2;
    }
    float q[4];
#pragma unroll
    for (int o = 0; o < 4; o++) {
        float upd = 0.f;
#pragma unroll
        for (int c = 0; c < 4; c++) upd = fmaf(compat[o*4+c], comb[c], upd);
        q[o] = lu[o*NT+n] - upd;
    }
    float mx = fmaxf(fmaxf(q[0],q[1]), fmaxf(q[2],q[3]));
    float sum = 0.f;
#pragma unroll
    for (int c = 0; c < 4; c++) { q[c] = __expf(q[c]-mx); sum += q[c]; }
    float inv = 1.f / sum;
    if (last) {
#pragma unroll
        for (int c = 0; c < 4; c++) out[c*NT+n] = q[c] * inv;  // kernel-end flush
    } else {
#pragma unroll
        for (int c = 0; c < 4; c++) {
            float qq = q[c] * inv;
            if (COH) { stcp(&W[(R_U1+c)*NT+n], qq*s1); stcp(&W[(R_U2+c)*NT+n], qq*s2); }
            else     { W[(R_U1+c)*NT+n] = qq*s1;       W[(R_U2+c)*NT+n] = qq*s2; }
        }
    }
}

// ---------------------- zero the barrier flags (pre-kernel) -----------------
__global__ __launch_bounds__(256) void k_zero(float* __restrict__ W) {
    unsigned* sync = (unsigned*)(W + R_SY*NT);
#pragma unroll
    for (int i = 0; i < 16; i++) sync[threadIdx.x + i*256] = 0u;
}

// --------------------------- the single persistent kernel -------------------
__global__ __launch_bounds__(512) void k_crf_all(const float* __restrict__ lu,
        const float* __restrict__ feat, const float* __restrict__ compat,
        float* __restrict__ out, float* __restrict__ W) {
    __shared__ float SP[512 * 17];
    const int bid = blockIdx.x, tid = threadIdx.x;
    unsigned* sync = (unsigned*)(W + R_SY*NT);
    unsigned gen = 0;

    // ---- phase A: blocks 0..27 build + conv their own basis row (norm pass);
    //               blocks 28..115 compute closed-form scale2.
    if (bid < 28) {
        const int a = AB_A[bid], b = AB_B[bid];
        const float ca = INVSQF[a], cb = INVSQF[b];
        for (int s = tid; s < NT; s += 512) {
            float g0 = feat[s] * 0.2f, g1 = feat[NT + s] * 0.2f;
            float eg = ex2(-0.5f * LOG2E * (g0*g0 + g1*g1));
            float pa = 1.f;
            for (int i = 0; i < a; i++) pa *= g0;   // a,b wave-uniform (blockIdx)
            float pb = 1.f;
            for (int i = 0; i < b; i++) pb *= g1;
            float v = eg * pa * ca * pb * cb;
            stcp(&W[(R_M + bid)*NT + s], v);        // sc1: fresh at first cached read
            SP[(s >> 4)*17 + (s & 15)] = v;
        }
        conv3d_store512(SP, W + (R_CV + bid)*NT, tid);
    } else {
        const int nb = (bid - 28) * 94 + tid;       // 88 blocks x 94 >= 8192
        if (tid < 94 && nb < NT) {
            int x = nb >> 8, y = (nb >> 4) & 15, z = nb & 15;
            float Sx = 0.f, Sy = 0.f, Sz = 0.f;
            for (int j = 0; j < 32; j++) { float d = (float)(x-j)*INVA; Sx += ex2(-0.5f*d*d); }
            for (int j = 0; j < 16; j++) { float d = (float)(y-j)*INVA; Sy += ex2(-0.5f*d*d); }
            for (int j = 0; j < 16; j++) { float d = (float)(z-j)*INVA; Sz += ex2(-0.5f*d*d); }
            stcp(&W[R_S2*NT + nb], rsqrtf(Sx * Sy * Sz));
        }
    }
    gsync(sync, ++gen);

    // ---- init: rowsum contract -> scale1, q0, u1, u2
    { int n = bid * PPB + tid; if (tid < PPB && n < NT) init_point<true>(W, lu, n); }
    gsync(sync, ++gen);

    // ---- 5 mean-field iterations: conv(116 vols) -> fuse -> repeat
    for (int it = 0; it < 5; ++it) {
        {
            const int idx = bid;
            // Staging: prefetch all 16 sc1 loads into registers FIRST (MLP),
            // then combine with cached M reads and scatter into LDS.
            float rv[16];
            if (idx < 112) {
                const float* Mr = W + (R_M + (idx >> 2))*NT;   // cached (read-only)
                const float* ur = W + (R_U1 + (idx & 3))*NT;   // mutable: sc1
#pragma unroll
                for (int i = 0; i < 16; i++) rv[i] = ldcp(&ur[tid + i*512]);
#pragma unroll
                for (int i = 0; i < 16; i++) {
                    int s = tid + i*512;
                    SP[(s >> 4)*17 + (s & 15)] = Mr[s] * rv[i];
                }
            } else {
                const float* ur = W + (R_U2 + (idx - 112))*NT;
#pragma unroll
                for (int i = 0; i < 16; i++) rv[i] = ldcp(&ur[tid + i*512]);
#pragma unroll
                for (int i = 0; i < 16; i++) {
                    int s = tid + i*512;
                    SP[(s >> 4)*17 + (s & 15)] = rv[i];
                }
            }
            conv3d_store512(SP, W + (R_CV + idx)*NT, tid);
        }
        gsync(sync, ++gen);
        { int n = bid * PPB + tid; if (tid < PPB && n < NT) fuse_point<true>(W, lu, compat, out, n, it == 4); }
        if (it < 4) gsync(sync, ++gen);
    }
}

// --------------------------- fallback multi-kernel path ---------------------
__global__ __launch_bounds__(256) void k_setup(const float* __restrict__ feat,
                                               float* __restrict__ W) {
    int n = blockIdx.x * 256 + threadIdx.x;
    float g0 = feat[n] * 0.2f, g1 = feat[NT + n] * 0.2f;
    float eg = ex2(-0.5f * LOG2E * (g0*g0 + g1*g1));
    float p0[7], p1[7];
    p0[0] = 1.f; p1[0] = 1.f;
#pragma unroll
    for (int i = 1; i < 7; i++) { p0[i] = p0[i-1]*g0; p1[i] = p1[i-1]*g1; }
    int ab = 0;
#pragma unroll
    for (int k = 0; k <= 6; k++)
#pragma unroll
        for (int a = k; a >= 0; a--) {
            int b = k - a;
            W[(R_M + ab)*NT + n] = eg * p0[a]*INVSQF[a] * p1[b]*INVSQF[b];
            ab++;
        }
    int x = n >> 8, y = (n >> 4) & 15, z = n & 15;
    float Sx = 0.f, Sy = 0.f, Sz = 0.f;
    for (int j = 0; j < 32; j++) { float d = (float)(x-j)*INVA; Sx += ex2(-0.5f*d*d); }
    for (int j = 0; j < 16; j++) { float d = (float)(y-j)*INVA; Sy += ex2(-0.5f*d*d); }
    for (int j = 0; j < 16; j++) { float d = (float)(z-j)*INVA; Sz += ex2(-0.5f*d*d); }
    W[R_S2*NT + n] = rsqrtf(Sx * Sy * Sz);
}

__global__ __launch_bounds__(256) void k_conv(const float* __restrict__ W,
                                              float* __restrict__ Wout, int mode) {
    __shared__ float SP[512 * 17];
    const int idx = blockIdx.x;
    const int tid = threadIdx.x;
    if (mode == 0) {
        const float* src = W + (R_M + idx) * NT;
        for (int s = tid; s < NT; s += 256)
            SP[(s >> 4)*17 + (s & 15)] = src[s];
    } else if (idx < 112) {
        const float* Mr = W + (R_M + (idx >> 2)) * NT;
        const float* ur = W + (R_U1 + (idx & 3)) * NT;
        for (int s = tid; s < NT; s += 256)
            SP[(s >> 4)*17 + (s & 15)] = Mr[s] * ur[s];
    } else {
        const float* ur = W + (R_U2 + (idx - 112)) * NT;
        for (int s = tid; s < NT; s += 256)
            SP[(s >> 4)*17 + (s & 15)] = ur[s];
    }
    conv3d_store256(SP, Wout + (R_CV + idx)*NT, tid);
}

__global__ __launch_bounds__(256) void k_init(float* __restrict__ W,
                                              const float* __restrict__ lu) {
    int n = blockIdx.x * 256 + threadIdx.x;
    init_point<false>(W, lu, n);
}

__global__ __launch_bounds__(256) void k_fuse(float* __restrict__ W,
        const float* __restrict__ lu, const float* __restrict__ compat,
        float* __restrict__ out, int last) {
    int n = blockIdx.x * 256 + threadIdx.x;
    fuse_point<false>(W, lu, compat, out, n, last);
}

// ---------------------------------------------------------------- driver
extern "C" void kernel_launch(void* const* d_in, const int* in_sizes, int n_in,
                              void* d_out, int out_size, void* d_ws, size_t ws_size,
                              hipStream_t stream) {
    const float* lu     = (const float*)d_in[0];
    const float* feat   = (const float*)d_in[1];
    const float* compat = (const float*)d_in[2];
    float* out = (float*)d_out;
    float* W   = (float*)d_ws;     // needs 158*NT*4 = 5.2 MB

    k_zero<<<dim3(1), dim3(256), 0, stream>>>(W);   // zero barrier flags

    void* args[] = {(void*)&lu, (void*)&feat, (void*)&compat, (void*)&out, (void*)&W};
    hipError_t rc = hipLaunchCooperativeKernel((const void*)k_crf_all,
                                               dim3(NBLK), dim3(512), args, 0, stream);
    if (rc != hipSuccess) {
        (void)hipGetLastError();   // clear, fall back to multi-launch path
        k_setup<<<dim3(32), dim3(256), 0, stream>>>(feat, W);
        k_conv <<<dim3(28), dim3(256), 0, stream>>>(W, W, 0);
        k_init <<<dim3(32), dim3(256), 0, stream>>>(W, lu);
        for (int it = 0; it < 5; it++) {
            k_conv<<<dim3(116), dim3(256), 0, stream>>>(W, W, 1);
            k_fuse<<<dim3(32),  dim3(256), 0, stream>>>(W, lu, compat, out, it == 4);
        }
    }
}

// Round 7
// 139.635 us; speedup vs baseline: 3.3961x; 3.3961x over previous
//
#include <hip/hip_runtime.h>
#include <math.h>

// CRF mean-field, fully factorized — NO O(N^2) pass.
// MULTI-LAUNCH (12 dispatches). Persistent-kernel route abandoned after R1-R5:
// any intra-kernel grid sync on MI355X forces cross-block data through HBM
// (sc1 = no L2/L3 allocation; fences = whole-L2 flush) -> ~30 us/phase floor,
// 366-555 us total. Kernel boundaries are the cheap cross-XCD coherence.
// Dispatches: k_phaseA (basis+norm-conv, merged) ; k_init (incl closed-form
// scale2) ; 5 x { k_conv(116 vols) ; k_fuse }.
// Bilateral kernel rank-28 Taylor basis (degree 6), separable 3-D Gaussian
// convs, 5 mean-field iterations. N = 32*16*16 = 8192, C = 4.

constexpr int   NT    = 8192;
constexpr float LOG2E = 1.4426950408889634f;
constexpr float SQL2E = 1.2011224087864498f;     // sqrt(log2 e)
constexpr float INVA  = 0.2f * SQL2E;            // spatial prescale

// W rows (NT floats each):
//   0..27 : M[ab]   32..35 : u1[c]   36..39 : u2[c]
//   40 : scale1   41 : scale2   42..157 : conv outputs
constexpr int R_M = 0, R_U1 = 32, R_U2 = 36, R_S1 = 40, R_S2 = 41, R_CV = 42;

static __device__ __forceinline__ float ex2(float x) {
    return __builtin_amdgcn_exp2f(x);
}

__constant__ float INVSQF[7] = {1.f, 1.f, 0.70710678f, 0.40824829f,
                                0.20412415f, 0.09128709f, 0.03726780f};
// ab -> (a,b) enumeration: for k=0..6, a=k..0, b=k-a (must match contract order)
__constant__ int AB_A[28] = {0, 1,0, 2,1,0, 3,2,1,0, 4,3,2,1,0,
                             5,4,3,2,1,0, 6,5,4,3,2,1,0};
__constant__ int AB_B[28] = {0, 0,1, 0,1,2, 0,1,2,3, 0,1,2,3,4,
                             0,1,2,3,4,5, 0,1,2,3,4,5,6};

// ---------------- separable 3-D Gaussian conv, 512-thread version -----------
// SP staged as SP[(n>>4)*17 + (n&15)]; caller stages, we sync first.
static __device__ __forceinline__ void conv3d_store512(float* SP,
                                                       float* __restrict__ outp,
                                                       int tid) {
    float g32[32];
#pragma unroll
    for (int d = 0; d < 32; d++) { float t = d * INVA; g32[d] = ex2(-0.5f*t*t); }
    __syncthreads();
    // z-pass: 512 rows (x,y), one per thread, stride 17
    {
        int r = tid;
        float v[16], acc[16];
#pragma unroll
        for (int z = 0; z < 16; z++) { v[z] = SP[r*17 + z]; acc[z] = 0.f; }
#pragma unroll
        for (int zp = 0; zp < 16; zp++)
#pragma unroll
            for (int z = 0; z < 16; z++) {
                int d = (z > zp) ? (z - zp) : (zp - z);
                acc[z] = fmaf(g32[d], v[zp], acc[z]);
            }
#pragma unroll
        for (int z = 0; z < 16; z++) SP[r*17 + z] = acc[z];
    }
    __syncthreads();
    // y-pass: 512 rows (x,z), one per thread, stride 17 between y's
    {
        int x = tid >> 4, z = tid & 15;
        int base = x * 272 + z;
        float v[16], acc[16];
#pragma unroll
        for (int y = 0; y < 16; y++) { v[y] = SP[base + y*17]; acc[y] = 0.f; }
#pragma unroll
        for (int yp = 0; yp < 16; yp++)
#pragma unroll
            for (int y = 0; y < 16; y++) {
                int d = (y > yp) ? (y - yp) : (yp - y);
                acc[y] = fmaf(g32[d], v[yp], acc[y]);
            }
#pragma unroll
        for (int y = 0; y < 16; y++) SP[base + y*17] = acc[y];
    }
    __syncthreads();
    // x-pass: 256 columns (y,z), 2 threads/column; h wave-uniform (tid>>8)
    // so all g32 indices stay compile-time constants (no scratch spill).
    {
        int c = tid & 255, h = tid >> 8;
        int base = (c >> 4) * 17 + (c & 15);     // 17*y + z
        float v[32];
#pragma unroll
        for (int xp = 0; xp < 32; xp++) v[xp] = SP[base + xp*272];
        float acc[16];
#pragma unroll
        for (int x0 = 0; x0 < 16; x0++) acc[x0] = 0.f;
        if (h == 0) {
#pragma unroll
            for (int xp = 0; xp < 32; xp++)
#pragma unroll
                for (int x0 = 0; x0 < 16; x0++) {
                    int d = (x0 > xp) ? (x0 - xp) : (xp - x0);
                    acc[x0] = fmaf(g32[d], v[xp], acc[x0]);
                }
#pragma unroll
            for (int x0 = 0; x0 < 16; x0++) outp[x0*256 + c] = acc[x0];
        } else {
#pragma unroll
            for (int xp = 0; xp < 32; xp++)
#pragma unroll
                for (int x0 = 0; x0 < 16; x0++) {
                    int x = x0 + 16;
                    int d = (x > xp) ? (x - xp) : (xp - x);
                    acc[x0] = fmaf(g32[d], v[xp], acc[x0]);
                }
#pragma unroll
            for (int x0 = 0; x0 < 16; x0++) outp[(x0+16)*256 + c] = acc[x0];
        }
    }
}

// ---------------- phase A: build basis row + norm-pass conv (merged) --------
__global__ __launch_bounds__(512) void k_phaseA(const float* __restrict__ feat,
                                                float* __restrict__ W) {
    __shared__ float SP[512 * 17];
    const int bid = blockIdx.x, tid = threadIdx.x;
    const int a = AB_A[bid], b = AB_B[bid];
    const float ca = INVSQF[a], cb = INVSQF[b];
    for (int s = tid; s < NT; s += 512) {
        float g0 = feat[s] * 0.2f, g1 = feat[NT + s] * 0.2f;
        float eg = ex2(-0.5f * LOG2E * (g0*g0 + g1*g1));
        float pa = 1.f;
        for (int i = 0; i < a; i++) pa *= g0;    // a,b wave-uniform (blockIdx)
        float pb = 1.f;
        for (int i = 0; i < b; i++) pb *= g1;
        float v = eg * pa * ca * pb * cb;
        W[(R_M + bid)*NT + s] = v;
        SP[(s >> 4)*17 + (s & 15)] = v;
    }
    conv3d_store512(SP, W + (R_CV + bid)*NT, tid);
}

// ---------------- init: closed-form scale2, rowsum->scale1, q0, u1, u2 ------
__global__ __launch_bounds__(256) void k_init(float* __restrict__ W,
                                              const float* __restrict__ lu) {
    int n = blockIdx.x * 256 + threadIdx.x;
    // closed-form spatial rowsum (exact separable product) -> scale2
    int x = n >> 8, y = (n >> 4) & 15, z = n & 15;
    float Sx = 0.f, Sy = 0.f, Sz = 0.f;
    for (int j = 0; j < 32; j++) { float d = (float)(x-j)*INVA; Sx += ex2(-0.5f*d*d); }
    for (int j = 0; j < 16; j++) { float d = (float)(y-j)*INVA; Sy += ex2(-0.5f*d*d); }
    for (int j = 0; j < 16; j++) { float d = (float)(z-j)*INVA; Sz += ex2(-0.5f*d*d); }
    float s2 = rsqrtf(Sx * Sy * Sz);
    W[R_S2*NT + n] = s2;
    // bilateral rowsum: rank-28 contract of M against norm-pass conv outputs
    float rs = 0.f;
#pragma unroll
    for (int ab = 0; ab < 28; ab++)
        rs = fmaf(W[(R_M+ab)*NT + n], W[(R_CV+ab)*NT + n], rs);
    float s1 = rsqrtf(rs);
    W[R_S1*NT + n] = s1;
    float l0 = lu[n], l1 = lu[NT+n], l2 = lu[2*NT+n], l3 = lu[3*NT+n];
    float mx = fmaxf(fmaxf(l0,l1), fmaxf(l2,l3));
    float q0 = __expf(l0-mx), q1 = __expf(l1-mx), q2 = __expf(l2-mx), q3 = __expf(l3-mx);
    float inv = 1.f / (q0+q1+q2+q3);
    q0*=inv; q1*=inv; q2*=inv; q3*=inv;
    W[(R_U1+0)*NT+n]=q0*s1; W[(R_U1+1)*NT+n]=q1*s1; W[(R_U1+2)*NT+n]=q2*s1; W[(R_U1+3)*NT+n]=q3*s1;
    W[(R_U2+0)*NT+n]=q0*s2; W[(R_U2+1)*NT+n]=q1*s2; W[(R_U2+2)*NT+n]=q2*s2; W[(R_U2+3)*NT+n]=q3*s2;
}

// ---------------- iteration conv: 116 volumes, float4 staging ---------------
__global__ __launch_bounds__(512) void k_conv(const float* __restrict__ W,
                                              float* __restrict__ Wout) {
    __shared__ float SP[512 * 17];
    const int idx = blockIdx.x;
    const int tid = threadIdx.x;
    if (idx < 112) {
        const float4* M4 = (const float4*)(W + (R_M + (idx >> 2))*NT);
        const float4* U4 = (const float4*)(W + (R_U1 + (idx & 3))*NT);
#pragma unroll
        for (int i = 0; i < 4; i++) {
            int s4 = tid + i*512;                // float4 index; s = 4*s4
            float4 m = M4[s4], u = U4[s4];
            int s = s4 << 2;
            int base = (s >> 4)*17 + (s & 15);   // s&15 in {0,4,8,12}: same row
            SP[base+0] = m.x*u.x; SP[base+1] = m.y*u.y;
            SP[base+2] = m.z*u.z; SP[base+3] = m.w*u.w;
        }
    } else {
        const float4* U4 = (const float4*)(W + (R_U2 + (idx - 112))*NT);
#pragma unroll
        for (int i = 0; i < 4; i++) {
            int s4 = tid + i*512;
            float4 u = U4[s4];
            int s = s4 << 2;
            int base = (s >> 4)*17 + (s & 15);
            SP[base+0] = u.x; SP[base+1] = u.y; SP[base+2] = u.z; SP[base+3] = u.w;
        }
    }
    conv3d_store512(SP, Wout + (R_CV + idx)*NT, tid);
}

// ---------------- fuse: rank-28 contract, combine, compat, softmax, next u --
__global__ __launch_bounds__(256) void k_fuse(float* __restrict__ W,
        const float* __restrict__ lu, const float* __restrict__ compat,
        float* __restrict__ out, int last) {
    int n = blockIdx.x * 256 + threadIdx.x;
    float s1 = W[R_S1*NT + n], s2 = W[R_S2*NT + n];
    float q1[4] = {0.f, 0.f, 0.f, 0.f};
#pragma unroll
    for (int ab = 0; ab < 28; ab++) {
        float m = W[(R_M+ab)*NT + n];
#pragma unroll
        for (int c = 0; c < 4; c++)
            q1[c] = fmaf(m, W[(R_CV + ab*4 + c)*NT + n], q1[c]);
    }
    float comb[4];
#pragma unroll
    for (int c = 0; c < 4; c++)
        comb[c] = s1 * q1[c] + s2 * W[(R_CV + 112 + c)*NT + n];
    float q[4];
#pragma unroll
    for (int o = 0; o < 4; o++) {
        float upd = 0.f;
#pragma unroll
        for (int c = 0; c < 4; c++) upd = fmaf(compat[o*4+c], comb[c], upd);
        q[o] = lu[o*NT+n] - upd;
    }
    float mx = fmaxf(fmaxf(q[0],q[1]), fmaxf(q[2],q[3]));
    float sum = 0.f;
#pragma unroll
    for (int c = 0; c < 4; c++) { q[c] = __expf(q[c]-mx); sum += q[c]; }
    float inv = 1.f / sum;
    if (last) {
#pragma unroll
        for (int c = 0; c < 4; c++) out[c*NT+n] = q[c] * inv;
    } else {
#pragma unroll
        for (int c = 0; c < 4; c++) {
            float qq = q[c] * inv;
            W[(R_U1+c)*NT+n] = qq*s1;
            W[(R_U2+c)*NT+n] = qq*s2;
        }
    }
}

// ---------------------------------------------------------------- driver
extern "C" void kernel_launch(void* const* d_in, const int* in_sizes, int n_in,
                              void* d_out, int out_size, void* d_ws, size_t ws_size,
                              hipStream_t stream) {
    const float* lu     = (const float*)d_in[0];
    const float* feat   = (const float*)d_in[1];
    const float* compat = (const float*)d_in[2];
    float* out = (float*)d_out;
    float* W   = (float*)d_ws;     // needs 158*NT*4 = 5.2 MB

    k_phaseA<<<dim3(28),  dim3(512), 0, stream>>>(feat, W);   // basis + norm conv
    k_init  <<<dim3(32),  dim3(256), 0, stream>>>(W, lu);     // s2, s1, q0, u1, u2
    for (int it = 0; it < 5; it++) {
        k_conv<<<dim3(116), dim3(512), 0, stream>>>(W, W);
        k_fuse<<<dim3(32),  dim3(256), 0, stream>>>(W, lu, compat, out, it == 4);
    }
}

// Round 8
// 131.075 us; speedup vs baseline: 3.6179x; 1.0653x over previous
//
#include <hip/hip_runtime.h>
#include <math.h>

// CRF mean-field, fully factorized — NO O(N^2) pass.
// MULTI-LAUNCH, 12 dispatches (structural minimum: fuse->conv merge needs a
// cross-block reduce, and mutable cross-kernel data can't be L2-cached without
// kernel boundaries — R2-R5 showed coherence-point traffic costs ~30us/phase).
// This round: conv epilogue pre-multiplies s1*M (bilateral) / s2 (spatial) so
// k_fuse's rank-28 contract becomes a plain 29-term sum; phaseA pre-multiplies
// M for the norm pass (k_init rowsum = plain sum); closed-form scale2 moved to
// phaseA's 4 spare blocks.
// Bilateral kernel rank-28 Taylor basis (degree 6), separable 3-D Gaussian
// convs, 5 mean-field iterations. N = 32*16*16 = 8192, C = 4.

constexpr int   NT    = 8192;
constexpr float LOG2E = 1.4426950408889634f;
constexpr float SQL2E = 1.2011224087864498f;     // sqrt(log2 e)
constexpr float INVA  = 0.2f * SQL2E;            // spatial prescale

// W rows (NT floats each):
//   0..27 : M[ab]   32..35 : u1[c]   36..39 : u2[c]
//   40 : scale1   41 : scale2   42..157 : conv outputs (pre-multiplied)
constexpr int R_M = 0, R_U1 = 32, R_U2 = 36, R_S1 = 40, R_S2 = 41, R_CV = 42;

static __device__ __forceinline__ float ex2(float x) {
    return __builtin_amdgcn_exp2f(x);
}

__constant__ float INVSQF[7] = {1.f, 1.f, 0.70710678f, 0.40824829f,
                                0.20412415f, 0.09128709f, 0.03726780f};
// ab -> (a,b) enumeration: for k=0..6, a=k..0, b=k-a (must match contract order)
__constant__ int AB_A[28] = {0, 1,0, 2,1,0, 3,2,1,0, 4,3,2,1,0,
                             5,4,3,2,1,0, 6,5,4,3,2,1,0};
__constant__ int AB_B[28] = {0, 0,1, 0,1,2, 0,1,2,3, 0,1,2,3,4,
                             0,1,2,3,4,5, 0,1,2,3,4,5,6};

// ---------------- separable 3-D Gaussian conv, 512-thread version -----------
// SP staged as SP[(n>>4)*17 + (n&15)]; caller stages, we sync first.
// Epilogue: out(n) = wrow0[n]*wrow1[n]*acc  (wrow1 may be null -> 1.0).
static __device__ __forceinline__ void conv3d_store512(float* SP,
                                                       float* __restrict__ outp,
                                                       const float* w0,
                                                       const float* w1,
                                                       int tid) {
    float g32[32];
#pragma unroll
    for (int d = 0; d < 32; d++) { float t = d * INVA; g32[d] = ex2(-0.5f*t*t); }
    __syncthreads();
    // z-pass: 512 rows (x,y), one per thread, stride 17
    {
        int r = tid;
        float v[16], acc[16];
#pragma unroll
        for (int z = 0; z < 16; z++) { v[z] = SP[r*17 + z]; acc[z] = 0.f; }
#pragma unroll
        for (int zp = 0; zp < 16; zp++)
#pragma unroll
            for (int z = 0; z < 16; z++) {
                int d = (z > zp) ? (z - zp) : (zp - z);
                acc[z] = fmaf(g32[d], v[zp], acc[z]);
            }
#pragma unroll
        for (int z = 0; z < 16; z++) SP[r*17 + z] = acc[z];
    }
    __syncthreads();
    // y-pass: 512 rows (x,z), one per thread, stride 17 between y's
    {
        int x = tid >> 4, z = tid & 15;
        int base = x * 272 + z;
        float v[16], acc[16];
#pragma unroll
        for (int y = 0; y < 16; y++) { v[y] = SP[base + y*17]; acc[y] = 0.f; }
#pragma unroll
        for (int yp = 0; yp < 16; yp++)
#pragma unroll
            for (int y = 0; y < 16; y++) {
                int d = (y > yp) ? (y - yp) : (yp - y);
                acc[y] = fmaf(g32[d], v[yp], acc[y]);
            }
#pragma unroll
        for (int y = 0; y < 16; y++) SP[base + y*17] = acc[y];
    }
    __syncthreads();
    // x-pass: 256 columns (y,z), 2 threads/column; h wave-uniform (tid>>8)
    // so all g32 indices stay compile-time constants (no scratch spill).
    {
        int c = tid & 255, h = tid >> 8;
        int base = (c >> 4) * 17 + (c & 15);     // 17*y + z
        float v[32];
#pragma unroll
        for (int xp = 0; xp < 32; xp++) v[xp] = SP[base + xp*272];
        float acc[16];
#pragma unroll
        for (int x0 = 0; x0 < 16; x0++) acc[x0] = 0.f;
        if (h == 0) {
#pragma unroll
            for (int xp = 0; xp < 32; xp++)
#pragma unroll
                for (int x0 = 0; x0 < 16; x0++) {
                    int d = (x0 > xp) ? (x0 - xp) : (xp - x0);
                    acc[x0] = fmaf(g32[d], v[xp], acc[x0]);
                }
#pragma unroll
            for (int x0 = 0; x0 < 16; x0++) {
                int n = x0*256 + c;
                float w = w0 ? w0[n] : 1.f;
                if (w1) w *= w1[n];
                outp[n] = w * acc[x0];
            }
        } else {
#pragma unroll
            for (int xp = 0; xp < 32; xp++)
#pragma unroll
                for (int x0 = 0; x0 < 16; x0++) {
                    int x = x0 + 16;
                    int d = (x > xp) ? (x - xp) : (xp - x);
                    acc[x0] = fmaf(g32[d], v[xp], acc[x0]);
                }
#pragma unroll
            for (int x0 = 0; x0 < 16; x0++) {
                int n = (x0+16)*256 + c;
                float w = w0 ? w0[n] : 1.f;
                if (w1) w *= w1[n];
                outp[n] = w * acc[x0];
            }
        }
    }
}

// ---------------- phase A: basis + norm conv (premul M); spare blocks: s2 ---
__global__ __launch_bounds__(512) void k_phaseA(const float* __restrict__ feat,
                                                float* __restrict__ W) {
    __shared__ float SP[512 * 17];
    const int bid = blockIdx.x, tid = threadIdx.x;
    if (bid < 28) {
        const int a = AB_A[bid], b = AB_B[bid];
        const float ca = INVSQF[a], cb = INVSQF[b];
        for (int s = tid; s < NT; s += 512) {
            float g0 = feat[s] * 0.2f, g1 = feat[NT + s] * 0.2f;
            float eg = ex2(-0.5f * LOG2E * (g0*g0 + g1*g1));
            float pa = 1.f;
            for (int i = 0; i < a; i++) pa *= g0;    // a,b wave-uniform
            float pb = 1.f;
            for (int i = 0; i < b; i++) pb *= g1;
            float v = eg * pa * ca * pb * cb;
            W[(R_M + bid)*NT + s] = v;
            SP[(s >> 4)*17 + (s & 15)] = v;
        }
        // epilogue multiplies by M(n) (re-read own row; drained by barriers,
        // same XCD/L2) -> norm CV is pre-multiplied: k_init rowsum = plain sum
        conv3d_store512(SP, W + (R_CV + bid)*NT, W + (R_M + bid)*NT, nullptr, tid);
    } else {
        // blocks 28..31: closed-form scale2 (exact separable product)
#pragma unroll
        for (int i = 0; i < 4; i++) {
            int n = (bid - 28) * 2048 + i*512 + tid;
            int x = n >> 8, y = (n >> 4) & 15, z = n & 15;
            float Sx = 0.f, Sy = 0.f, Sz = 0.f;
            for (int j = 0; j < 32; j++) { float d = (float)(x-j)*INVA; Sx += ex2(-0.5f*d*d); }
            for (int j = 0; j < 16; j++) { float d = (float)(y-j)*INVA; Sy += ex2(-0.5f*d*d); }
            for (int j = 0; j < 16; j++) { float d = (float)(z-j)*INVA; Sz += ex2(-0.5f*d*d); }
            W[R_S2*NT + n] = rsqrtf(Sx * Sy * Sz);
        }
    }
}

// ---------------- init: rowsum (plain sum) -> scale1, q0, u1, u2 ------------
__global__ __launch_bounds__(256) void k_init(float* __restrict__ W,
                                              const float* __restrict__ lu) {
    int n = blockIdx.x * 256 + threadIdx.x;
    float rs = 0.f;
#pragma unroll
    for (int ab = 0; ab < 28; ab++)
        rs += W[(R_CV+ab)*NT + n];            // pre-multiplied by M in phaseA
    float s1 = rsqrtf(rs);
    float s2 = W[R_S2*NT + n];
    W[R_S1*NT + n] = s1;
    float l0 = lu[n], l1 = lu[NT+n], l2 = lu[2*NT+n], l3 = lu[3*NT+n];
    float mx = fmaxf(fmaxf(l0,l1), fmaxf(l2,l3));
    float q0 = __expf(l0-mx), q1 = __expf(l1-mx), q2 = __expf(l2-mx), q3 = __expf(l3-mx);
    float inv = 1.f / (q0+q1+q2+q3);
    q0*=inv; q1*=inv; q2*=inv; q3*=inv;
    W[(R_U1+0)*NT+n]=q0*s1; W[(R_U1+1)*NT+n]=q1*s1; W[(R_U1+2)*NT+n]=q2*s1; W[(R_U1+3)*NT+n]=q3*s1;
    W[(R_U2+0)*NT+n]=q0*s2; W[(R_U2+1)*NT+n]=q1*s2; W[(R_U2+2)*NT+n]=q2*s2; W[(R_U2+3)*NT+n]=q3*s2;
}

// ---------------- iteration conv: 116 volumes; epilogue premul s*M ----------
__global__ __launch_bounds__(512) void k_conv(const float* __restrict__ W,
                                              float* __restrict__ Wout) {
    __shared__ float SP[512 * 17];
    const int idx = blockIdx.x;
    const int tid = threadIdx.x;
    if (idx < 112) {
        const float4* M4 = (const float4*)(W + (R_M + (idx >> 2))*NT);
        const float4* U4 = (const float4*)(W + (R_U1 + (idx & 3))*NT);
#pragma unroll
        for (int i = 0; i < 4; i++) {
            int s4 = tid + i*512;                // float4 index; s = 4*s4
            float4 m = M4[s4], u = U4[s4];
            int s = s4 << 2;
            int base = (s >> 4)*17 + (s & 15);   // s&15 in {0,4,8,12}: same row
            SP[base+0] = m.x*u.x; SP[base+1] = m.y*u.y;
            SP[base+2] = m.z*u.z; SP[base+3] = m.w*u.w;
        }
        // out = s1(n)*M(n)*conv  -> fuse contract becomes a plain sum
        conv3d_store512(SP, Wout + (R_CV + idx)*NT,
                        W + (R_M + (idx >> 2))*NT, W + R_S1*NT, tid);
    } else {
        const float4* U4 = (const float4*)(W + (R_U2 + (idx - 112))*NT);
#pragma unroll
        for (int i = 0; i < 4; i++) {
            int s4 = tid + i*512;
            float4 u = U4[s4];
            int s = s4 << 2;
            int base = (s >> 4)*17 + (s & 15);
            SP[base+0] = u.x; SP[base+1] = u.y; SP[base+2] = u.z; SP[base+3] = u.w;
        }
        // out = s2(n)*conv
        conv3d_store512(SP, Wout + (R_CV + idx)*NT, W + R_S2*NT, nullptr, tid);
    }
}

// ---------------- fuse: 29-term sum, compat, softmax, next u ----------------
__global__ __launch_bounds__(256) void k_fuse(float* __restrict__ W,
        const float* __restrict__ lu, const float* __restrict__ compat,
        float* __restrict__ out, int last) {
    int n = blockIdx.x * 256 + threadIdx.x;
    float comb[4] = {0.f, 0.f, 0.f, 0.f};
#pragma unroll
    for (int ab = 0; ab < 28; ab++)
#pragma unroll
        for (int c = 0; c < 4; c++)
            comb[c] += W[(R_CV + ab*4 + c)*NT + n];   // premul s1*M in conv
#pragma unroll
    for (int c = 0; c < 4; c++)
        comb[c] += W[(R_CV + 112 + c)*NT + n];        // premul s2 in conv
    float q[4];
#pragma unroll
    for (int o = 0; o < 4; o++) {
        float upd = 0.f;
#pragma unroll
        for (int c = 0; c < 4; c++) upd = fmaf(compat[o*4+c], comb[c], upd);
        q[o] = lu[o*NT+n] - upd;
    }
    float mx = fmaxf(fmaxf(q[0],q[1]), fmaxf(q[2],q[3]));
    float sum = 0.f;
#pragma unroll
    for (int c = 0; c < 4; c++) { q[c] = __expf(q[c]-mx); sum += q[c]; }
    float inv = 1.f / sum;
    if (last) {
#pragma unroll
        for (int c = 0; c < 4; c++) out[c*NT+n] = q[c] * inv;
    } else {
        float s1 = W[R_S1*NT + n], s2 = W[R_S2*NT + n];
#pragma unroll
        for (int c = 0; c < 4; c++) {
            float qq = q[c] * inv;
            W[(R_U1+c)*NT+n] = qq*s1;
            W[(R_U2+c)*NT+n] = qq*s2;
        }
    }
}

// ---------------------------------------------------------------- driver
extern "C" void kernel_launch(void* const* d_in, const int* in_sizes, int n_in,
                              void* d_out, int out_size, void* d_ws, size_t ws_size,
                              hipStream_t stream) {
    const float* lu     = (const float*)d_in[0];
    const float* feat   = (const float*)d_in[1];
    const float* compat = (const float*)d_in[2];
    float* out = (float*)d_out;
    float* W   = (float*)d_ws;     // needs 158*NT*4 = 5.2 MB

    k_phaseA<<<dim3(32),  dim3(512), 0, stream>>>(feat, W);   // basis+norm conv+s2
    k_init  <<<dim3(32),  dim3(256), 0, stream>>>(W, lu);     // s1, q0, u1, u2
    for (int it = 0; it < 5; it++) {
        k_conv<<<dim3(116), dim3(512), 0, stream>>>(W, W);
        k_fuse<<<dim3(32),  dim3(256), 0, stream>>>(W, lu, compat, out, it == 4);
    }
}